// Round 9
// baseline (137.162 us; speedup 1.0000x reference)
//
#include <hip/hip_runtime.h>
#include <math.h>

// ALCOVE cell: B=256, D=64, H=2048, O=32
// RHO=2, TAU=1, BETA=6.5, GAMMA=0, PHI=2, LAM_A=0.001, LAM_W=0.003
//
// R12 == R10/R11 with the nontemporal-store compile fix:
// __builtin_nontemporal_store needs a clang ext_vector_type, not HIP's
// float4 class -> store through a native float4 alias (vfloat4).
//
// R10 theory (untested until now):
//   1) HARD register pin asm("" : "+v"(x)) on all 16 areg float4 after
//      phase 1: compiler cannot rematerialize the assoc loads (R9: VGPR
//      stuck at 60 -> loads re-issued in phases 2/3, assoc read 2-3x
//      from L3). Signal: VGPR >= 120.
//   2) Non-temporal stores for the 66 MB write-once assoc update -> no
//      L2 write-allocate pollution evicting ct/coords while phase 4
//      reads coords under the store drain.
// Arithmetic/summation order identical to R7/R9 -> bitwise-identical.
//
// ws: ct [D*H] only (512 KB, L2-resident transpose of coords).

#define BB 256
#define DD 64
#define HH 2048
#define OO 32
#define BETA 6.5f
#define PHI 2.0f
#define LAM_A 0.001f
#define LAM_W 0.003f
#define NT0 256
#define NT 1024
#define NW (NT / 64)            // 16 waves
#define NCH (HH / (NT / 8))     // 16 assoc chunks per thread

typedef float vfloat4 __attribute__((ext_vector_type(4)));  // native vec for nt-store

__global__ __launch_bounds__(NT0) void k0_transpose(
    const float* __restrict__ coords, float* __restrict__ ct)
{
    int idx = blockIdx.x * NT0 + threadIdx.x;   // 0 .. D*H-1, ct-linear
    int d = idx >> 11;                          // / HH
    int h = idx & (HH - 1);
    ct[idx] = coords[h * DD + d];
}

__global__ __launch_bounds__(NT) void k_cell(
    const float* __restrict__ z,
    const float* __restrict__ one_hot,
    const float* __restrict__ att,
    const float* __restrict__ assoc,
    const float* __restrict__ coords,
    const float* __restrict__ ct,
    float* __restrict__ out)
{
    __shared__ float2 za[DD];           // (z_d, att_d)
    __shared__ float  s_loc[HH];        // 8 KB: similarity s
    __shared__ float  rc_loc[HH];       // 8 KB: r = -beta*s/(2d), then coeff
    __shared__ float  wredf[NW * OO];   // 2 KB: per-wave x_out partials
    __shared__ float  redf[NT];         // 4 KB: g_att reduction
    __shared__ float  gx_s[OO];

    const int b = blockIdx.x;
    const int t = threadIdx.x;
    const int o4 = t & 7;        // float4 column (o = o4*4 + comp)
    const int hl = t >> 3;       // 0..127

    if (t < DD)
        za[t] = make_float2(z[b * DD + t], att[b * DD + t]);
    __syncthreads();

    // ---- issue all 16 assoc loads NOW (after the barrier, so no drain);
    //      they complete under phase-1 compute; hard-pinned below ----
    const float4* assoc4 = (const float4*)(assoc + (size_t)b * HH * OO);
    float4 areg[NCH];
    #pragma unroll
    for (int ch = 0; ch < NCH; ++ch)
        areg[ch] = assoc4[(ch * (NT / 8) + hl) * (OO / 4) + o4];

    // ---- phase 1: distance/similarity for all 2048 h ----
    #pragma unroll
    for (int i = 0; i < HH / NT; ++i) {          // 2 rounds of 1024 h
        const int h = i * NT + t;
        float S = 0.0f;
        const float* ctp = ct + h;
        #pragma unroll 16
        for (int d = 0; d < DD; ++d) {
            float2 p = za[d];                    // broadcast ds_read_b64
            float c = ctp[d * HH];               // coalesced, L2-hit
            float diff = p.x - c;
            S = fmaf(p.y * diff, diff, S);
        }
        S = S < 0.0f ? 0.0f : S;
        float dd = sqrtf(S);
        float sh = expf(-BETA * dd);
        s_loc[h]  = sh;
        rc_loc[h] = (dd > 0.0f) ? (-BETA * sh / (2.0f * dd)) : 0.0f;
    }
    // HARD pin: "+v" makes each component opaque -> compiler cannot
    // rematerialize the loads; 64 VGPRs stay live through phases 2/3.
    #pragma unroll
    for (int ch = 0; ch < NCH; ++ch)
        asm volatile("" : "+v"(areg[ch].x), "+v"(areg[ch].y),
                         "+v"(areg[ch].z), "+v"(areg[ch].w));
    __syncthreads();

    // ---- phase 2: x_out from registers ----
    float4 acc = make_float4(0.f, 0.f, 0.f, 0.f);
    #pragma unroll
    for (int ch = 0; ch < NCH; ++ch) {
        int hloc = ch * (NT / 8) + hl;
        float s2 = s_loc[hloc];                  // 8-way broadcast, conflict-free
        float4 a = areg[ch];
        acc.x = fmaf(s2, a.x, acc.x);
        acc.y = fmaf(s2, a.y, acc.y);
        acc.z = fmaf(s2, a.z, acc.z);
        acc.w = fmaf(s2, a.w, acc.w);
    }
    // reduce over the 8 hl-rows inside each wave (lane bits 3..5)
    #pragma unroll
    for (int m = 8; m <= 32; m <<= 1) {
        acc.x += __shfl_xor(acc.x, m, 64);
        acc.y += __shfl_xor(acc.y, m, 64);
        acc.z += __shfl_xor(acc.z, m, 64);
        acc.w += __shfl_xor(acc.w, m, 64);
    }
    if ((t & 63) < 8) {                          // lane o4 of each wave
        int w = t >> 6;
        wredf[w * OO + o4 * 4 + 0] = acc.x;
        wredf[w * OO + o4 * 4 + 1] = acc.y;
        wredf[w * OO + o4 * 4 + 2] = acc.z;
        wredf[w * OO + o4 * 4 + 3] = acc.w;
    }
    __syncthreads();

    // ---- gx + output 0 (t < 32; o == t) ----
    if (t < OO) {
        float x = 0.0f;
        #pragma unroll
        for (int w = 0; w < NW; ++w)
            x += wredf[w * OO + t];              // conflict-free rows
        float oh = one_hot[b * OO + t];
        float tmin = fminf(-1.0f, x);
        float tmax = fmaxf(1.0f, x);
        float teacher = tmin - oh * tmin + oh * tmax;
        gx_s[t] = (2.0f / OO) * (x - teacher);
        out[b * OO + t] = PHI * x;               // output 0
    }
    __syncthreads();

    // ---- phase 3a: g_s -> coeff (LDS + shfl only, uses areg) ----
    const float4 gxv = ((const float4*)gx_s)[o4];
    #pragma unroll
    for (int ch = 0; ch < NCH; ++ch) {
        int hloc = ch * (NT / 8) + hl;
        float4 a = areg[ch];
        float part = a.x * gxv.x + a.y * gxv.y + a.z * gxv.z + a.w * gxv.w;
        part += __shfl_xor(part, 1, 64);
        part += __shfl_xor(part, 2, 64);
        part += __shfl_xor(part, 4, 64);
        if (o4 == 0)
            rc_loc[hloc] *= part;                // coeff = r * g_s
    }
    __syncthreads();    // cheap: no vmem outstanding; publishes rc_loc

    // ---- phase 3b: fire assoc-update stores, non-temporal (no wait) ----
    {
        vfloat4* out_assoc4 = (vfloat4*)(out + BB * OO + BB * DD)
                            + (size_t)b * HH * (OO / 4);
        #pragma unroll
        for (int ch = 0; ch < NCH; ++ch) {
            int hloc = ch * (NT / 8) + hl;
            float4 a = areg[ch];
            float w = LAM_W * s_loc[hloc];
            vfloat4 na;
            na.x = fmaf(-w, gxv.x, a.x);
            na.y = fmaf(-w, gxv.y, a.y);
            na.z = fmaf(-w, gxv.z, a.z);
            na.w = fmaf(-w, gxv.w, a.w);
            // write-once stream: bypass L2 allocate (keeps ct/coords hot)
            __builtin_nontemporal_store(na, &out_assoc4[hloc * (OO / 4) + o4]);
        }
    }

    // ---- phase 4: g_att compute; stores drain underneath (no barrier) ----
    {
        const int lane = t & 63, wv = t >> 6;
        const float zd = za[lane].x;
        float ga = 0.0f;
        #pragma unroll 8
        for (int i = 0; i < HH / NW; ++i) {      // 128 h per wave
            int hloc = wv * (HH / NW) + i;
            float cf = rc_loc[hloc];             // same-address broadcast
            float c = coords[(size_t)hloc * DD + lane];  // coalesced, L2-hit
            float diff = zd - c;
            ga = fmaf(cf * diff, diff, ga);
        }
        redf[t] = ga;
    }
    // LDS-only barrier: redf visibility without draining the assoc stores
    asm volatile("s_waitcnt lgkmcnt(0)\n\ts_barrier" ::: "memory");

    if (t < DD) {
        float g = 0.0f;
        #pragma unroll
        for (int w = 0; w < NW; ++w)
            g += redf[w * 64 + t];               // conflict-free rows
        float na = att[b * DD + t] - LAM_A * g;
        out[BB * OO + b * DD + t] = na > 0.0f ? na : 0.0f;   // output 1
    }
    // kernel end drains the assoc stores
}

extern "C" void kernel_launch(void* const* d_in, const int* in_sizes, int n_in,
                              void* d_out, int out_size, void* d_ws, size_t ws_size,
                              hipStream_t stream) {
    const float* z       = (const float*)d_in[0];
    const float* one_hot = (const float*)d_in[1];
    const float* att     = (const float*)d_in[2];
    const float* assoc   = (const float*)d_in[3];
    const float* coords  = (const float*)d_in[4];
    float* out = (float*)d_out;

    float* ct = (float*)d_ws;                    // D*H floats

    k0_transpose<<<dim3((DD * HH) / NT0), dim3(NT0), 0, stream>>>(coords, ct);
    k_cell<<<dim3(BB), dim3(NT), 0, stream>>>(z, one_hot, att, assoc,
                                              coords, ct, out);
}